// Round 8
// baseline (178.094 us; speedup 1.0000x reference)
//
#include <hip/hip_runtime.h>
#include <math.h>

#define NE 1600000
#define NN 100000
#define NBKT 391    // ceil(NN/256): 256-node buckets
#define PCH 3200    // edges per k_binpay block: 500 * 3200 == NE exactly
#define PGRID 500
#define CBIN 8192
#define NCBLK ((NE + CBIN - 1) / CBIN)  // 196

typedef __attribute__((ext_vector_type(8))) short bf16x8;
typedef __attribute__((ext_vector_type(4))) float f32x4;
typedef __attribute__((ext_vector_type(4))) unsigned int u32x4;

static __device__ inline short f2bf(float f) {
  unsigned u = __float_as_uint(f);
  u += 0x7FFFu + ((u >> 16) & 1u);
  return (short)(u >> 16);
}

static __device__ inline unsigned int pack2(float a, float b) {
  return (unsigned int)(unsigned short)f2bf(a) | ((unsigned int)(unsigned short)f2bf(b) << 16);
}

static __device__ inline void unpack2(unsigned int u, float& lo, float& hi) {
  lo = __uint_as_float(u << 16);
  hi = __uint_as_float(u & 0xffff0000u);
}

// W -> bf16 fragment order: Wf[(kt*4+ct)*64*8 + l*8 + i] = W[col][k]
__global__ void k_wprep(const float* __restrict__ W, short* __restrict__ Wf) {
  int j = blockIdx.x * 256 + threadIdx.x;
  if (j < 12 * 4 * 64 * 8) {
    int i = j & 7, l = (j >> 3) & 63, ct = (j >> 9) & 3, kt = j >> 11;
    int col = ct * 16 + (l & 15);
    int k = kt * 32 + (l >> 4) * 8 + i;
    Wf[j] = f2bf(W[col * 384 + k]);
  }
}

__global__ void k_zerob(int* __restrict__ bktcnt) {
  int t = threadIdx.x;
  if (t < NBKT) bktcnt[t] = 0;
}

// Coarse histogram over 256-node buckets: LDS hist, one global atomic/bucket.
__global__ __launch_bounds__(256) void k_bktcount(const int* __restrict__ dst,
                                                  int* __restrict__ bktcnt) {
  __shared__ int hist[NBKT];
  int t = threadIdx.x;
  for (int j = t; j < NBKT; j += 256) hist[j] = 0;
  __syncthreads();
  int start = blockIdx.x * CBIN;
  int lim = min(CBIN, NE - start);
  for (int j = t; j < lim; j += 256) atomicAdd(&hist[dst[start + j] >> 8], 1);
  __syncthreads();
  for (int j = t; j < NBKT; j += 256) {
    int h = hist[j];
    if (h) atomicAdd(&bktcnt[j], h);
  }
}

// Scan 391 bucket counts -> region bases + cursors.
__global__ void k_bktscan(const int* __restrict__ bktcnt, int* __restrict__ bktoff,
                          int* __restrict__ bkcur, int* __restrict__ off) {
  __shared__ int s[512];
  int t = threadIdx.x;
  int v = (t < NBKT) ? bktcnt[t] : 0;
  s[t] = v;
  __syncthreads();
  for (int d = 1; d < 512; d <<= 1) {
    int x = (t >= d) ? s[t - d] : 0;
    __syncthreads();
    s[t] += x;
    __syncthreads();
  }
  if (t < NBKT) {
    int ex = s[t] - v;
    bktoff[t] = ex;
    bkcur[t] = ex;
  }
  if (t == 0) {
    bktoff[NBKT] = NE;
    off[NN] = NE;
  }
}

// Payload binning, v2: per 64-edge tile, all 64 lanes reserve slots with one
// independent LDS atomic each; 8 sub-rounds then distribute q via shfl so the
// wave reads 8 consecutive 128B rows (1KB contiguous) and writes 8 full 64B
// rows per sub-round -- 8 independent chains in flight. 2 blocks/CU.
__global__ __launch_bounds__(768) void k_binpay(const float* __restrict__ msg,
                                                const int* __restrict__ dst,
                                                int* __restrict__ bkcur,
                                                unsigned int* __restrict__ pay,
                                                int* __restrict__ pdst) {
  __shared__ int sdst[PCH];
  __shared__ int hist[NBKT];
  int t = threadIdx.x;
  int start = blockIdx.x * PCH;  // exact: PGRID*PCH == NE
  for (int j = t; j < NBKT; j += 768) hist[j] = 0;
  __syncthreads();
  for (int j = t; j < PCH; j += 768) {
    int d = dst[start + j];
    sdst[j] = d;
    atomicAdd(&hist[d >> 8], 1);
  }
  __syncthreads();
  for (int j = t; j < NBKT; j += 768) {
    int h = hist[j];
    hist[j] = h ? atomicAdd(&bkcur[j], h) : 0;  // hist becomes local cursor
  }
  __syncthreads();
  int wid = t >> 6, lane = t & 63;
  int oct = lane >> 3, qt = lane & 7;
  for (int tb = wid * 64; tb < PCH; tb += 12 * 64) {  // 50 tiles over 12 waves
    int myn = sdst[tb + lane];
    int q = atomicAdd(&hist[myn >> 8], 1);  // per-lane slot, independent
#pragma unroll
    for (int s = 0; s < 8; s++) {
      int src = s * 8 + oct;
      int qq = __shfl(q, src);
      int e = start + tb + src;
      f32x4 v = *(const f32x4*)(msg + (size_t)e * 32 + qt * 4);
      unsigned int u0 = pack2(v[0], v[1]);
      unsigned int u1 = pack2(v[2], v[3]);
      *(uint2*)(pay + (size_t)qq * 16 + qt * 2) = make_uint2(u0, u1);
      if (qt == 0) pdst[qq] = sdst[tb + src];
    }
  }
}

// One block per bucket: per-node count+scan in LDS, off[] written contiguously,
// eid[p] = pay-row index, scattered within the bucket's 16KB window.
__global__ __launch_bounds__(256) void k_build(const int* __restrict__ pdst,
                                               const int* __restrict__ bktoff,
                                               int* __restrict__ off,
                                               int* __restrict__ eid) {
  __shared__ int cnt[256];
  __shared__ int loc[256];
  int b = blockIdx.x, t = threadIdx.x;
  int base = bktoff[b];
  int m = bktoff[b + 1] - base;
  cnt[t] = 0;
  __syncthreads();
  for (int i = t; i < m; i += 256) atomicAdd(&cnt[pdst[base + i] & 255], 1);
  __syncthreads();
  int v = cnt[t];
  loc[t] = v;
  __syncthreads();
  for (int d = 1; d < 256; d <<= 1) {
    int x = (t >= d) ? loc[t - d] : 0;
    __syncthreads();
    loc[t] += x;
    __syncthreads();
  }
  int ex = base + loc[t] - v;
  int node = b * 256 + t;
  if (node < NN) off[node] = ex;
  __syncthreads();
  loc[t] = ex;
  __syncthreads();
  for (int i = t; i < m; i += 256) {
    int n = pdst[base + i];
    int p = atomicAdd(&loc[n & 255], 1);
    eid[p] = base + i;  // pay row index
  }
}

// Fused gather + stats + MFMA. Gathers 64B bf16 rows from pay via eid; all of
// a wave's reads fall inside its own bucket's ~262KB region (window-local).
// Wave = 16 nodes; lane l: node r=l&15, channel octet oct=l>>4.
__global__ __launch_bounds__(256, 6) void k_fusedS(const unsigned int* __restrict__ pay,
                                                   const int* __restrict__ off,
                                                   const int* __restrict__ eid,
                                                   const short* __restrict__ Wf,
                                                   const float* __restrict__ bias,
                                                   float* __restrict__ out) {
  int wid = threadIdx.x >> 6, lane = threadIdx.x & 63;
  int r = lane & 15, oct = lane >> 4;
  int nb = (blockIdx.x * 4 + wid) * 16;
  if (nb >= NN) return;
  int node = nb + r;

  int e0 = off[node], e1 = off[node + 1];

  float sv[8], qv[8], xv[8], nv[8];
#pragma unroll
  for (int i = 0; i < 8; i++) {
    sv[i] = 0.f;
    qv[i] = 0.f;
    xv[i] = -INFINITY;
    nv[i] = INFINITY;
  }

  int p = e0;
  int nfull = (e1 - e0) >> 2;
  int ea0 = 0, ea1 = 0, ea2 = 0, ea3 = 0;
  if (nfull > 0) {
    ea0 = eid[p];
    ea1 = eid[p + 1];
    ea2 = eid[p + 2];
    ea3 = eid[p + 3];
  }
  for (int it = 0; it < nfull; ++it) {
    int c0 = ea0, c1 = ea1, c2 = ea2, c3 = ea3;
    p += 4;
    if (it + 1 < nfull) {
      ea0 = eid[p];
      ea1 = eid[p + 1];
      ea2 = eid[p + 2];
      ea3 = eid[p + 3];
    }
    u32x4 U0 = *(const u32x4*)(pay + (size_t)c0 * 16 + oct * 4);
    u32x4 U1 = *(const u32x4*)(pay + (size_t)c1 * 16 + oct * 4);
    u32x4 U2 = *(const u32x4*)(pay + (size_t)c2 * 16 + oct * 4);
    u32x4 U3 = *(const u32x4*)(pay + (size_t)c3 * 16 + oct * 4);
#pragma unroll
    for (int j = 0; j < 4; j++) {
      float a0, b0, a1, b1, a2, b2, a3, b3;
      unpack2(U0[j], a0, b0);
      unpack2(U1[j], a1, b1);
      unpack2(U2[j], a2, b2);
      unpack2(U3[j], a3, b3);
      int i0 = 2 * j, i1 = 2 * j + 1;
      sv[i0] += a0 + a1 + a2 + a3;
      qv[i0] += a0 * a0 + a1 * a1 + a2 * a2 + a3 * a3;
      xv[i0] = fmaxf(fmaxf(xv[i0], fmaxf(a0, a1)), fmaxf(a2, a3));
      nv[i0] = fminf(fminf(nv[i0], fminf(a0, a1)), fminf(a2, a3));
      sv[i1] += b0 + b1 + b2 + b3;
      qv[i1] += b0 * b0 + b1 * b1 + b2 * b2 + b3 * b3;
      xv[i1] = fmaxf(fmaxf(xv[i1], fmaxf(b0, b1)), fmaxf(b2, b3));
      nv[i1] = fminf(fminf(nv[i1], fminf(b0, b1)), fminf(b2, b3));
    }
  }
  for (; p < e1; ++p) {
    int e = eid[p];
    u32x4 U = *(const u32x4*)(pay + (size_t)e * 16 + oct * 4);
#pragma unroll
    for (int j = 0; j < 4; j++) {
      float a, b;
      unpack2(U[j], a, b);
      int i0 = 2 * j, i1 = 2 * j + 1;
      sv[i0] += a;
      qv[i0] += a * a;
      xv[i0] = fmaxf(xv[i0], a);
      nv[i0] = fminf(nv[i0], a);
      sv[i1] += b;
      qv[i1] += b * b;
      xv[i1] = fmaxf(xv[i1], b);
      nv[i1] = fminf(nv[i1], b);
    }
  }

  float degr = (float)(e1 - e0);
  float deg = fmaxf(degr, 1.f);
  float inv = 1.f / deg;
  float amp = logf(deg + 1.f);
  float att = 1.f / (deg + 1.f);

#pragma unroll
  for (int i = 0; i < 8; i++) {
    float me = sv[i] * inv;
    float va = fmaxf(qv[i] * inv - me * me, 0.f);
    sv[i] = me;                 // mean
    qv[i] = sqrtf(va + 1e-8f);  // std
    xv[i] = (xv[i] == -INFINITY) ? 0.f : xv[i];
    nv[i] = (nv[i] == INFINITY) ? 0.f : nv[i];
  }

  f32x4 acc[4] = {{0.f, 0.f, 0.f, 0.f},
                  {0.f, 0.f, 0.f, 0.f},
                  {0.f, 0.f, 0.f, 0.f},
                  {0.f, 0.f, 0.f, 0.f}};
  float scal[3] = {1.f, amp, att};
  const bf16x8* Bp = (const bf16x8*)Wf;
#pragma unroll
  for (int kt = 0; kt < 12; kt++) {
    const float* ag = (kt < 3) ? sv : (kt < 6) ? xv : (kt < 9) ? nv : qv;
    float sc = scal[kt % 3];
    bf16x8 b0 = Bp[(kt * 4 + 0) * 64 + lane];
    bf16x8 b1 = Bp[(kt * 4 + 1) * 64 + lane];
    bf16x8 b2 = Bp[(kt * 4 + 2) * 64 + lane];
    bf16x8 b3 = Bp[(kt * 4 + 3) * 64 + lane];
    bf16x8 af;
#pragma unroll
    for (int i = 0; i < 8; i++) af[i] = f2bf(ag[i] * sc);
    acc[0] = __builtin_amdgcn_mfma_f32_16x16x32_bf16(af, b0, acc[0], 0, 0, 0);
    acc[1] = __builtin_amdgcn_mfma_f32_16x16x32_bf16(af, b1, acc[1], 0, 0, 0);
    acc[2] = __builtin_amdgcn_mfma_f32_16x16x32_bf16(af, b2, acc[2], 0, 0, 0);
    acc[3] = __builtin_amdgcn_mfma_f32_16x16x32_bf16(af, b3, acc[3], 0, 0, 0);
    __builtin_amdgcn_sched_barrier(0);
  }

#pragma unroll
  for (int ct = 0; ct < 4; ct++) {
    int ocol = ct * 16 + r;
    float bb = bias[ocol];
#pragma unroll
    for (int j = 0; j < 4; j++) {
      int orow = nb + oct * 4 + j;
      out[orow * 64 + ocol] = acc[ct][j] + bb;
    }
  }
}

extern "C" void kernel_launch(void* const* d_in, const int* in_sizes, int n_in,
                              void* d_out, int out_size, void* d_ws, size_t ws_size,
                              hipStream_t stream) {
  const float* msg = (const float*)d_in[0];
  const int* dst = (const int*)d_in[1];
  const float* W = (const float*)d_in[3];
  const float* bias = (const float*)d_in[4];
  float* out = (float*)d_out;

  unsigned int* pay = (unsigned int*)d_ws;       // NE*16 uints (64B bf16 rows)
  int* pdst = (int*)(pay + (size_t)NE * 16);     // NE
  int* eid = pdst + NE;                          // NE
  int* off = eid + NE;                           // NN+1
  int* bktcnt = off + NN + 1;                    // NBKT
  int* bktoff = bktcnt + NBKT;                   // NBKT+1
  int* bkcur = bktoff + NBKT + 1;                // NBKT
  short* Wfrag = (short*)(bkcur + NBKT);         // 24576 shorts

  k_wprep<<<96, 256, 0, stream>>>(W, Wfrag);
  k_zerob<<<1, 512, 0, stream>>>(bktcnt);
  k_bktcount<<<NCBLK, 256, 0, stream>>>(dst, bktcnt);
  k_bktscan<<<1, 512, 0, stream>>>(bktcnt, bktoff, bkcur, off);
  k_binpay<<<PGRID, 768, 0, stream>>>(msg, dst, bkcur, pay, pdst);
  k_build<<<NBKT, 256, 0, stream>>>(pdst, bktoff, off, eid);
  k_fusedS<<<(NN / 16 + 3) / 4, 256, 0, stream>>>(pay, off, eid, Wfrag, bias, out);
}

// Round 9
// 114.881 us; speedup vs baseline: 1.5503x; 1.5503x over previous
//
#include <hip/hip_runtime.h>
#include <math.h>

#define NE 1600000
#define NN 100000
#define NBKT 391    // ceil(NN/256): 256-node buckets
#define CBIN 8192
#define NCBLK ((NE + CBIN - 1) / CBIN)  // 196

typedef __attribute__((ext_vector_type(8))) short bf16x8;
typedef __attribute__((ext_vector_type(4))) float f32x4;

static __device__ inline short f2bf(float f) {
  unsigned u = __float_as_uint(f);
  u += 0x7FFFu + ((u >> 16) & 1u);
  return (short)(u >> 16);
}

// Fused prep: W -> bf16 fragment order, and zero the bucket counters.
// Wf[(kt*4+ct)*64*8 + l*8 + i] = W[col][k], col=ct*16+(l&15), k=kt*32+(l>>4)*8+i
__global__ void k_prep0(const float* __restrict__ W, short* __restrict__ Wf,
                        int* __restrict__ bktcnt) {
  int j = blockIdx.x * 256 + threadIdx.x;
  if (j < 12 * 4 * 64 * 8) {
    int i = j & 7, l = (j >> 3) & 63, ct = (j >> 9) & 3, kt = j >> 11;
    int col = ct * 16 + (l & 15);
    int k = kt * 32 + (l >> 4) * 8 + i;
    Wf[j] = f2bf(W[col * 384 + k]);
  }
  if (j < NBKT) bktcnt[j] = 0;
}

// Coarse histogram over 256-node buckets: LDS hist, one global atomic/bucket.
__global__ __launch_bounds__(256) void k_bktcount(const int* __restrict__ dst,
                                                  int* __restrict__ bktcnt) {
  __shared__ int hist[NBKT];
  int t = threadIdx.x;
  for (int j = t; j < NBKT; j += 256) hist[j] = 0;
  __syncthreads();
  int start = blockIdx.x * CBIN;
  int lim = min(CBIN, NE - start);  // 8192 or 2560; both %4 == 0
  for (int j = 4 * t; j + 4 <= lim; j += 1024) {
    int4 d4 = *(const int4*)(dst + start + j);
    atomicAdd(&hist[d4.x >> 8], 1);
    atomicAdd(&hist[d4.y >> 8], 1);
    atomicAdd(&hist[d4.z >> 8], 1);
    atomicAdd(&hist[d4.w >> 8], 1);
  }
  __syncthreads();
  for (int j = t; j < NBKT; j += 256) {
    int h = hist[j];
    if (h) atomicAdd(&bktcnt[j], h);
  }
}

// Scan 391 bucket counts -> region bases + cursors.
__global__ void k_bktscan(const int* __restrict__ bktcnt, int* __restrict__ bktoff,
                          int* __restrict__ bkcur, int* __restrict__ off) {
  __shared__ int s[512];
  int t = threadIdx.x;
  int v = (t < NBKT) ? bktcnt[t] : 0;
  s[t] = v;
  __syncthreads();
  for (int d = 1; d < 512; d <<= 1) {
    int x = (t >= d) ? s[t - d] : 0;
    __syncthreads();
    s[t] += x;
    __syncthreads();
  }
  if (t < NBKT) {
    int ex = s[t] - v;
    bktoff[t] = ex;
    bkcur[t] = ex;
  }
  if (t == 0) {
    bktoff[NBKT] = NE;
    off[NN] = NE;
  }
}

// Bin edges into bucket regions as (dst,e) pairs; fine atomics in LDS only;
// global writes are contiguous ~21-pair runs per (block,bucket).
__global__ __launch_bounds__(256) void k_bin(const int* __restrict__ dst,
                                             int* __restrict__ bkcur,
                                             int2* __restrict__ pairs) {
  __shared__ int sdst[CBIN];
  __shared__ int hist[NBKT];
  int t = threadIdx.x;
  int start = blockIdx.x * CBIN;
  int lim = min(CBIN, NE - start);
  for (int j = t; j < NBKT; j += 256) hist[j] = 0;
  __syncthreads();
  for (int j = 4 * t; j + 4 <= lim; j += 1024) {
    int4 d4 = *(const int4*)(dst + start + j);
    sdst[j] = d4.x;
    sdst[j + 1] = d4.y;
    sdst[j + 2] = d4.z;
    sdst[j + 3] = d4.w;
    atomicAdd(&hist[d4.x >> 8], 1);
    atomicAdd(&hist[d4.y >> 8], 1);
    atomicAdd(&hist[d4.z >> 8], 1);
    atomicAdd(&hist[d4.w >> 8], 1);
  }
  __syncthreads();
  for (int j = t; j < NBKT; j += 256) {
    int h = hist[j];
    hist[j] = h ? atomicAdd(&bkcur[j], h) : 0;  // hist becomes local cursor
  }
  __syncthreads();
  for (int j = t; j < lim; j += 256) {
    int d = sdst[j];
    int q = atomicAdd(&hist[d >> 8], 1);
    pairs[q] = make_int2(d, start + j);
  }
}

// One block per bucket: per-node count+scan in LDS, off[] written contiguously,
// eid scatter within the bucket's 16KB L2-resident window.
__global__ __launch_bounds__(256) void k_build(const int2* __restrict__ pairs,
                                               const int* __restrict__ bktoff,
                                               int* __restrict__ off,
                                               int* __restrict__ eid) {
  __shared__ int cnt[256];
  __shared__ int loc[256];
  int b = blockIdx.x, t = threadIdx.x;
  int base = bktoff[b];
  int m = bktoff[b + 1] - base;
  cnt[t] = 0;
  __syncthreads();
  for (int i = t; i < m; i += 256) atomicAdd(&cnt[pairs[base + i].x & 255], 1);
  __syncthreads();
  int v = cnt[t];
  loc[t] = v;
  __syncthreads();
  for (int d = 1; d < 256; d <<= 1) {
    int x = (t >= d) ? loc[t - d] : 0;
    __syncthreads();
    loc[t] += x;
    __syncthreads();
  }
  int ex = base + loc[t] - v;
  int node = b * 256 + t;
  if (node < NN) off[node] = ex;
  __syncthreads();
  loc[t] = ex;
  __syncthreads();
  for (int i = t; i < m; i += 256) {
    int2 pe = pairs[base + i];
    int p = atomicAdd(&loc[pe.x & 255], 1);
    eid[p] = pe.y;
  }
}

// Fused gather + stats + MFMA projection (round-5 proven version, no LDS).
// Wave = 16 nodes. Lane l: node r=l&15, channel octet oct=l>>4; lanes
// r,r+16,r+32,r+48 walk the same node -> 4x32B reads = one 128B row per edge.
// B-fragments broadcast from L2/L3-hot Wf in the epilogue.
__global__ __launch_bounds__(256, 6) void k_fused(const float* __restrict__ msg,
                                                  const int* __restrict__ off,
                                                  const int* __restrict__ eid,
                                                  const short* __restrict__ Wf,
                                                  const float* __restrict__ bias,
                                                  float* __restrict__ out) {
  int wid = threadIdx.x >> 6, lane = threadIdx.x & 63;
  int r = lane & 15, oct = lane >> 4;
  int nb = (blockIdx.x * 4 + wid) * 16;
  if (nb >= NN) return;  // NN % 16 == 0: surviving waves fully valid
  int node = nb + r;

  int e0 = off[node], e1 = off[node + 1];

  float sv[8], qv[8], xv[8], nv[8];
#pragma unroll
  for (int i = 0; i < 8; i++) {
    sv[i] = 0.f;
    qv[i] = 0.f;
    xv[i] = -INFINITY;
    nv[i] = INFINITY;
  }

  const float* mbase = msg + oct * 8;
  int p = e0;
  int nfull = (e1 - e0) >> 2;
  int ea0 = 0, ea1 = 0, ea2 = 0, ea3 = 0;
  if (nfull > 0) {
    ea0 = eid[p];
    ea1 = eid[p + 1];
    ea2 = eid[p + 2];
    ea3 = eid[p + 3];
  }
  for (int it = 0; it < nfull; ++it) {
    int c0 = ea0, c1 = ea1, c2 = ea2, c3 = ea3;
    p += 4;
    if (it + 1 < nfull) {  // prefetch next batch's eids past this batch's VALU
      ea0 = eid[p];
      ea1 = eid[p + 1];
      ea2 = eid[p + 2];
      ea3 = eid[p + 3];
    }
    const f32x4* r0 = (const f32x4*)(mbase + (size_t)c0 * 32);
    const f32x4* r1 = (const f32x4*)(mbase + (size_t)c1 * 32);
    const f32x4* r2 = (const f32x4*)(mbase + (size_t)c2 * 32);
    const f32x4* r3 = (const f32x4*)(mbase + (size_t)c3 * 32);
    f32x4 va0 = r0[0], vb0 = r0[1];
    f32x4 va1 = r1[0], vb1 = r1[1];
    f32x4 va2 = r2[0], vb2 = r2[1];
    f32x4 va3 = r3[0], vb3 = r3[1];
#pragma unroll
    for (int i = 0; i < 4; i++) {
      float w0 = va0[i], w1 = va1[i], w2 = va2[i], w3 = va3[i];
      sv[i] += w0 + w1 + w2 + w3;
      qv[i] += w0 * w0 + w1 * w1 + w2 * w2 + w3 * w3;
      xv[i] = fmaxf(fmaxf(xv[i], fmaxf(w0, w1)), fmaxf(w2, w3));
      nv[i] = fminf(fminf(nv[i], fminf(w0, w1)), fminf(w2, w3));
      float z0 = vb0[i], z1 = vb1[i], z2 = vb2[i], z3 = vb3[i];
      sv[i + 4] += z0 + z1 + z2 + z3;
      qv[i + 4] += z0 * z0 + z1 * z1 + z2 * z2 + z3 * z3;
      xv[i + 4] = fmaxf(fmaxf(xv[i + 4], fmaxf(z0, z1)), fmaxf(z2, z3));
      nv[i + 4] = fminf(fminf(nv[i + 4], fminf(z0, z1)), fminf(z2, z3));
    }
  }
  for (; p < e1; ++p) {
    int e = eid[p];
    const f32x4* rp = (const f32x4*)(mbase + (size_t)e * 32);
    f32x4 a = rp[0], b = rp[1];
#pragma unroll
    for (int i = 0; i < 4; i++) {
      float v0 = a[i], v1 = b[i];
      sv[i] += v0;
      qv[i] += v0 * v0;
      xv[i] = fmaxf(xv[i], v0);
      nv[i] = fminf(nv[i], v0);
      sv[i + 4] += v1;
      qv[i + 4] += v1 * v1;
      xv[i + 4] = fmaxf(xv[i + 4], v1);
      nv[i + 4] = fminf(nv[i + 4], v1);
    }
  }

  float degr = (float)(e1 - e0);
  float deg = fmaxf(degr, 1.f);
  float inv = 1.f / deg;
  float amp = logf(deg + 1.f);
  float att = 1.f / (deg + 1.f);

#pragma unroll
  for (int i = 0; i < 8; i++) {
    float me = sv[i] * inv;
    float va = fmaxf(qv[i] * inv - me * me, 0.f);
    sv[i] = me;                 // mean
    qv[i] = sqrtf(va + 1e-8f);  // std
    xv[i] = (xv[i] == -INFINITY) ? 0.f : xv[i];
    nv[i] = (nv[i] == INFINITY) ? 0.f : nv[i];
  }

  f32x4 acc[4] = {{0.f, 0.f, 0.f, 0.f},
                  {0.f, 0.f, 0.f, 0.f},
                  {0.f, 0.f, 0.f, 0.f},
                  {0.f, 0.f, 0.f, 0.f}};
  float scal[3] = {1.f, amp, att};
  const bf16x8* Bp = (const bf16x8*)Wf;
#pragma unroll
  for (int kt = 0; kt < 12; kt++) {
    const float* ag = (kt < 3) ? sv : (kt < 6) ? xv : (kt < 9) ? nv : qv;
    float sc = scal[kt % 3];
    bf16x8 b0 = Bp[(kt * 4 + 0) * 64 + lane];
    bf16x8 b1 = Bp[(kt * 4 + 1) * 64 + lane];
    bf16x8 b2 = Bp[(kt * 4 + 2) * 64 + lane];
    bf16x8 b3 = Bp[(kt * 4 + 3) * 64 + lane];
    bf16x8 af;
#pragma unroll
    for (int i = 0; i < 8; i++) af[i] = f2bf(ag[i] * sc);
    acc[0] = __builtin_amdgcn_mfma_f32_16x16x32_bf16(af, b0, acc[0], 0, 0, 0);
    acc[1] = __builtin_amdgcn_mfma_f32_16x16x32_bf16(af, b1, acc[1], 0, 0, 0);
    acc[2] = __builtin_amdgcn_mfma_f32_16x16x32_bf16(af, b2, acc[2], 0, 0, 0);
    acc[3] = __builtin_amdgcn_mfma_f32_16x16x32_bf16(af, b3, acc[3], 0, 0, 0);
    __builtin_amdgcn_sched_barrier(0);  // keep per-kt B-loads from all hoisting
  }

#pragma unroll
  for (int ct = 0; ct < 4; ct++) {
    int ocol = ct * 16 + r;
    float bb = bias[ocol];
#pragma unroll
    for (int j = 0; j < 4; j++) {
      int orow = nb + oct * 4 + j;
      out[orow * 64 + ocol] = acc[ct][j] + bb;
    }
  }
}

extern "C" void kernel_launch(void* const* d_in, const int* in_sizes, int n_in,
                              void* d_out, int out_size, void* d_ws, size_t ws_size,
                              hipStream_t stream) {
  const float* msg = (const float*)d_in[0];
  const int* dst = (const int*)d_in[1];
  const float* W = (const float*)d_in[3];
  const float* bias = (const float*)d_in[4];
  float* out = (float*)d_out;

  int* wsi = (int*)d_ws;
  int2* pairs = (int2*)wsi;               // 2*NE ints
  int* eid = wsi + 2 * NE;                // NE
  int* off = wsi + 3 * NE;                // NN+1
  int* bktcnt = wsi + 3 * NE + NN + 1;    // NBKT
  int* bktoff = bktcnt + NBKT;            // NBKT+1
  int* bkcur = bktoff + NBKT + 1;         // NBKT
  short* Wfrag = (short*)(bkcur + NBKT);  // 24576 shorts

  k_prep0<<<96, 256, 0, stream>>>(W, Wfrag, bktcnt);
  k_bktcount<<<NCBLK, 256, 0, stream>>>(dst, bktcnt);
  k_bktscan<<<1, 512, 0, stream>>>(bktcnt, bktoff, bkcur, off);
  k_bin<<<NCBLK, 256, 0, stream>>>(dst, bkcur, pairs);
  k_build<<<NBKT, 256, 0, stream>>>(pairs, bktoff, off, eid);
  k_fused<<<(NN / 16 + 3) / 4, 256, 0, stream>>>(msg, off, eid, Wfrag, bias, out);
}